// Round 1
// baseline (201.489 us; speedup 1.0000x reference)
//
#include <hip/hip_runtime.h>
#include <hip/hip_bf16.h>
#include <cstdint>

typedef __attribute__((ext_vector_type(8))) __bf16 bf16x8;
typedef __attribute__((ext_vector_type(4))) float f32x4;

typedef const __attribute__((address_space(1))) void* as1cvp;
typedef __attribute__((address_space(3))) void* as3vp;

__device__ __forceinline__ void gload_lds16(const void* g, void* l) {
  __builtin_amdgcn_global_load_lds((as1cvp)g, (as3vp)l, 16, 0, 0);
}

#define LOG2E 1.4426950408889634f

// ---------------- Kernel 1: K projection + RoPE + V^T ----------------
// x: [32768][1024] f32 ; wk: [128][1024] f32
// krot: [32768][128] bf16, d-index XOR-swizzled by ((t&7)<<3)
// vt:   [8][128][4096] bf16, t-low6 XOR-swizzled by ((d&7)<<3)
__global__ __launch_bounds__(256) void proj_rope_kernel(
    const float* __restrict__ x, const float* __restrict__ wk,
    __bf16* __restrict__ krot, __bf16* __restrict__ vt)
{
  __shared__ __bf16 smem[16384];      // A[128][64] | B[128][64]; epilogue alias: vl[128][128]
  __bf16* As = smem;
  __bf16* Bs = smem + 8192;
  const int tid = threadIdx.x;
  const int wid = tid >> 6;
  const int lane = tid & 63;
  const int m0 = blockIdx.x * 128;
  const int wm = (wid >> 1) * 64;
  const int wn = (wid & 1) * 64;

  f32x4 acc[4][4];
#pragma unroll
  for (int i = 0; i < 4; i++)
#pragma unroll
    for (int j = 0; j < 4; j++) acc[i][j] = (f32x4)0.f;

  const int r_st = tid >> 1;
  const int c_st = (tid & 1) * 32;

  for (int k0 = 0; k0 < 1024; k0 += 64) {
    const float* gx = x + (size_t)(m0 + r_st) * 1024 + k0 + c_st;
    const float* gw = wk + (size_t)r_st * 1024 + k0 + c_st;
#pragma unroll
    for (int c = 0; c < 4; c++) {
      f32x4 a0 = *(const f32x4*)(gx + c * 8);
      f32x4 a1 = *(const f32x4*)(gx + c * 8 + 4);
      f32x4 b0 = *(const f32x4*)(gw + c * 8);
      f32x4 b1 = *(const f32x4*)(gw + c * 8 + 4);
      bf16x8 av, bv;
#pragma unroll
      for (int jj = 0; jj < 4; jj++) {
        av[jj] = (__bf16)a0[jj]; av[4 + jj] = (__bf16)a1[jj];
        bv[jj] = (__bf16)b0[jj]; bv[4 + jj] = (__bf16)b1[jj];
      }
      int col = (c_st + c * 8) ^ ((r_st & 7) << 3);
      *(bf16x8*)&As[r_st * 64 + col] = av;
      *(bf16x8*)&Bs[r_st * 64 + col] = bv;
    }
    __syncthreads();
#pragma unroll
    for (int kk = 0; kk < 2; kk++) {
      bf16x8 afr[4], bfr[4];
#pragma unroll
      for (int mi = 0; mi < 4; mi++) {
        int row = wm + mi * 16 + (lane & 15);
        int col = (kk * 32 + (lane >> 4) * 8) ^ ((row & 7) << 3);
        afr[mi] = *(const bf16x8*)&As[row * 64 + col];
      }
#pragma unroll
      for (int ni = 0; ni < 4; ni++) {
        int row = wn + ni * 16 + (lane & 15);
        int col = (kk * 32 + (lane >> 4) * 8) ^ ((row & 7) << 3);
        bfr[ni] = *(const bf16x8*)&Bs[row * 64 + col];
      }
#pragma unroll
      for (int mi = 0; mi < 4; mi++)
#pragma unroll
        for (int ni = 0; ni < 4; ni++)
          acc[mi][ni] = __builtin_amdgcn_mfma_f32_16x16x32_bf16(afr[mi], bfr[ni], acc[mi][ni], 0, 0, 0);
    }
    __syncthreads();
  }

  // epilogue: RoPE + krot store + V^T via LDS transpose
  float cosv[4], sinv[4];
#pragma unroll
  for (int ni = 0; ni < 4; ni++) {
    int d = wn + ni * 16 + (lane & 15);
    float theta = exp2f((float)(d >> 1) * -0.20762050593046014f); // 10000^(-i/64)
    cosv[ni] = cosf(theta);
    sinv[ni] = sinf(theta);
  }
  __bf16* vl = smem; // [128][128]
  const bool evenlane = ((lane & 1) == 0);
#pragma unroll
  for (int mi = 0; mi < 4; mi++) {
#pragma unroll
    for (int r = 0; r < 4; r++) {
      int ml = wm + mi * 16 + (lane >> 4) * 4 + r;
      int mg = m0 + ml;
#pragma unroll
      for (int ni = 0; ni < 4; ni++) {
        float val = acc[mi][ni][r];
        int d = wn + ni * 16 + (lane & 15);
        vl[ml * 128 + d] = (__bf16)val;            // V = pre-RoPE k
        float partner = __shfl_xor(val, 1);
        float e = evenlane ? val : partner;
        float o = evenlane ? partner : val;
        float ev = e * cosv[ni] + o * sinv[ni];
        float od = -ev * sinv[ni] + o * cosv[ni];  // in-place slice semantics
        float kr = evenlane ? ev : od;
        krot[(size_t)mg * 128 + (d ^ ((mg & 7) << 3))] = (__bf16)kr;
      }
    }
  }
  __syncthreads();
  {
    int d = tid >> 1;
    int th = tid & 1;
    int b = m0 >> 12;
    int tb = (m0 & 4095) + th * 64;
    size_t base = ((size_t)b * 128 + d) * 4096 + tb;
#pragma unroll
    for (int c = 0; c < 8; c++) {
      bf16x8 w;
#pragma unroll
      for (int jj = 0; jj < 8; jj++) w[jj] = vl[(th * 64 + c * 8 + jj) * 128 + d];
      *(bf16x8*)&vt[base + ((c ^ (d & 7)) * 8)] = w;  // t-chunk swizzle baked in
    }
  }
}

// ---------------- Kernel 2: causal flash attention, Q = K_rot ----------------
__global__ __launch_bounds__(256) void attn_kernel(
    const __bf16* __restrict__ krot, const __bf16* __restrict__ vt,
    float* __restrict__ out)
{
  __shared__ __bf16 kl[64 * 128];   // K tile, row-swizzled
  __shared__ __bf16 vl[128 * 64];   // V^T tile, col-swizzled
  __shared__ __bf16 pl[4 * 16 * 72];// per-wave P, stride 72 kills A-frag conflicts
  const int tid = threadIdx.x;
  const int wid = tid >> 6;
  const int lane = tid & 63;
  const int b = blockIdx.x & 7;                  // batch -> XCD for L2 residency
  const int idx = (int)(blockIdx.x >> 3);        // 0..63
  const int qt = (idx < 32) ? (63 - idx) : (idx - 32); // big-first, balanced pairs
  const int q0 = qt * 64;
  const __bf16* kb = krot + (size_t)b * 4096 * 128;
  const __bf16* vb = vt + (size_t)b * 128 * 4096;

  bf16x8 qf[4];
  {
    int qrow = q0 + wid * 16 + (lane & 15);
    const __bf16* qp = kb + (size_t)qrow * 128;
#pragma unroll
    for (int ks = 0; ks < 4; ks++) {
      int col = (ks * 32 + (lane >> 4) * 8) ^ ((qrow & 7) << 3);
      qf[ks] = *(const bf16x8*)(qp + col);
    }
  }

  f32x4 acc[8];
#pragma unroll
  for (int i = 0; i < 8; i++) acc[i] = (f32x4)0.f;
  float m_r[4], l_r[4];
#pragma unroll
  for (int r = 0; r < 4; r++) { m_r[r] = -1e30f; l_r[r] = 0.f; }

  const float scale = 0.08838834764831845f; // 128^-0.5

  for (int j = 0; j <= qt; j++) {
    const int kv0 = j * 64;
    {
      const __bf16* src = kb + (size_t)kv0 * 128;   // 16KB contiguous
#pragma unroll
      for (int i = 0; i < 4; i++) {
        int blk = i * 4 + wid;
        gload_lds16(src + (size_t)(blk * 64 + lane) * 8, kl + blk * 512);
      }
#pragma unroll
      for (int i = 0; i < 4; i++) {
        int blk = i * 4 + wid;
        int o = blk * 64 + lane;
        gload_lds16(vb + (size_t)(o >> 3) * 4096 + kv0 + (o & 7) * 8, vl + blk * 512);
      }
    }
    __syncthreads();

    f32x4 S[4];
#pragma unroll
    for (int cb = 0; cb < 4; cb++) S[cb] = (f32x4)0.f;
#pragma unroll
    for (int cb = 0; cb < 4; cb++) {
      int kvl = cb * 16 + (lane & 15);
#pragma unroll
      for (int ks = 0; ks < 4; ks++) {
        int col = (ks * 32 + (lane >> 4) * 8) ^ ((kvl & 7) << 3);
        bf16x8 kf = *(const bf16x8*)&kl[kvl * 128 + col];
        S[cb] = __builtin_amdgcn_mfma_f32_16x16x32_bf16(qf[ks], kf, S[cb], 0, 0, 0);
      }
    }

    const bool diag = (j == qt);
    float pv[4][4];
#pragma unroll
    for (int r = 0; r < 4; r++) {
      int qg = q0 + wid * 16 + (lane >> 4) * 4 + r;
      float mx = -1e30f;
#pragma unroll
      for (int cb = 0; cb < 4; cb++) {
        float s = S[cb][r] * scale;
        if (diag && (kv0 + cb * 16 + (lane & 15)) > qg) s = -1e30f;
        pv[cb][r] = s;
        mx = fmaxf(mx, s);
      }
#pragma unroll
      for (int off = 1; off < 16; off <<= 1) mx = fmaxf(mx, __shfl_xor(mx, off));
      float mnew = fmaxf(m_r[r], mx);
      float alpha = exp2f((m_r[r] - mnew) * LOG2E);
      m_r[r] = mnew;
      float rs = 0.f;
#pragma unroll
      for (int cb = 0; cb < 4; cb++) {
        float p = exp2f((pv[cb][r] - mnew) * LOG2E);
        pv[cb][r] = p;
        rs += p;
      }
#pragma unroll
      for (int off = 1; off < 16; off <<= 1) rs += __shfl_xor(rs, off);
      l_r[r] = l_r[r] * alpha + rs;
#pragma unroll
      for (int db = 0; db < 8; db++) acc[db][r] *= alpha;
#pragma unroll
      for (int cb = 0; cb < 4; cb++)
        pl[wid * 1152 + ((lane >> 4) * 4 + r) * 72 + cb * 16 + (lane & 15)] = (__bf16)pv[cb][r];
    }

    bf16x8 pa[2];
#pragma unroll
    for (int k2 = 0; k2 < 2; k2++)
      pa[k2] = *(const bf16x8*)&pl[wid * 1152 + (lane & 15) * 72 + k2 * 32 + (lane >> 4) * 8];
#pragma unroll
    for (int db = 0; db < 8; db++) {
      int d = db * 16 + (lane & 15);
#pragma unroll
      for (int k2 = 0; k2 < 2; k2++) {
        int col = (k2 * 32 + (lane >> 4) * 8) ^ ((d & 7) << 3);
        bf16x8 vf = *(const bf16x8*)&vl[d * 64 + col];
        acc[db] = __builtin_amdgcn_mfma_f32_16x16x32_bf16(pa[k2], vf, acc[db], 0, 0, 0);
      }
    }
    __syncthreads();
  }

  float* op = out + (size_t)b * 4096 * 128;
#pragma unroll
  for (int r = 0; r < 4; r++) {
    float invl = 1.f / l_r[r];
    int qg = q0 + wid * 16 + (lane >> 4) * 4 + r;
#pragma unroll
    for (int db = 0; db < 8; db++)
      op[(size_t)qg * 128 + db * 16 + (lane & 15)] = acc[db][r] * invl;
  }
}

extern "C" void kernel_launch(void* const* d_in, const int* in_sizes, int n_in,
                              void* d_out, int out_size, void* d_ws, size_t ws_size,
                              hipStream_t stream) {
  const float* x  = (const float*)d_in[0];
  const float* wk = (const float*)d_in[1];
  __bf16* krot = (__bf16*)d_ws;                       // 8 MB
  __bf16* vt   = krot + (size_t)8 * 4096 * 128;       // 8 MB
  float* out   = (float*)d_out;
  proj_rope_kernel<<<256, 256, 0, stream>>>(x, wk, krot, vt);
  attn_kernel<<<512, 256, 0, stream>>>(krot, vt, out);
}

// Round 3
// 141.300 us; speedup vs baseline: 1.4260x; 1.4260x over previous
//
#include <hip/hip_runtime.h>
#include <hip/hip_bf16.h>
#include <cstdint>

typedef __attribute__((ext_vector_type(8))) __bf16 bf16x8;
typedef __attribute__((ext_vector_type(4))) float f32x4;
typedef __attribute__((ext_vector_type(16))) float f32x16;

typedef const __attribute__((address_space(1))) void* as1cvp;
typedef __attribute__((address_space(3))) void* as3vp;

__device__ __forceinline__ void gload_lds16(const void* g, void* l) {
  __builtin_amdgcn_global_load_lds((as1cvp)g, (as3vp)l, 16, 0, 0);
}
__device__ __forceinline__ float readlane_f(float v, int l) {
  return __uint_as_float((uint32_t)__builtin_amdgcn_readlane((int)__float_as_uint(v), l));
}

#define CEXP 0.1275179f   // 128^-0.5 * log2(e)

// V^T t-permutation within each 32-block: new pos p -> old t offset.
// Chunk c = p>>3 encodes (pk = c>>1, g = c&1); fragment slot j = p&7.
__device__ __forceinline__ int vperm(int p) {
  return 16 * (p >> 4) + 4 * ((p >> 3) & 1) + 8 * ((p >> 2) & 1) + (p & 3);
}

// ---------------- Kernel 1: K projection + RoPE + V^T ----------------
// x: [32768][1024] f32 ; wk: [128][1024] f32
// krot: [32768][128] bf16 LINEAR
// vt:   [8][128][4096] bf16, t permuted within each 32-block by vperm
__global__ __launch_bounds__(256) void proj_rope_kernel(
    const float* __restrict__ x, const float* __restrict__ wk,
    __bf16* __restrict__ krot, __bf16* __restrict__ vt)
{
  __shared__ __align__(16) char psmem[24576];
  __bf16* As = (__bf16*)psmem;            // [64][64] swizzled
  __bf16* Bs = (__bf16*)(psmem + 8192);   // [128][64] swizzled
  const int tid = threadIdx.x;
  const int wid = tid >> 6;
  const int lane = tid & 63;
  const int m0 = blockIdx.x * 64;
  const int wm = (wid >> 1) * 32;
  const int wn = (wid & 1) * 64;

  f32x4 acc[2][4];
#pragma unroll
  for (int i = 0; i < 2; i++)
#pragma unroll
    for (int j = 0; j < 4; j++) acc[i][j] = (f32x4)0.f;

  const int ar = tid >> 2, ac = (tid & 3) * 16;
  const int br = tid >> 1, bc = (tid & 1) * 32;

  for (int k0 = 0; k0 < 1024; k0 += 64) {
    const float* gx = x + (size_t)(m0 + ar) * 1024 + k0 + ac;
#pragma unroll
    for (int c = 0; c < 2; c++) {
      f32x4 a0 = *(const f32x4*)(gx + c * 8);
      f32x4 a1 = *(const f32x4*)(gx + c * 8 + 4);
      bf16x8 av;
#pragma unroll
      for (int jj = 0; jj < 4; jj++) { av[jj] = (__bf16)a0[jj]; av[4 + jj] = (__bf16)a1[jj]; }
      int col = (ac + c * 8) ^ ((ar & 7) << 3);
      *(bf16x8*)&As[ar * 64 + col] = av;
    }
    const float* gw = wk + (size_t)br * 1024 + k0 + bc;
#pragma unroll
    for (int c = 0; c < 4; c++) {
      f32x4 b0 = *(const f32x4*)(gw + c * 8);
      f32x4 b1 = *(const f32x4*)(gw + c * 8 + 4);
      bf16x8 bv;
#pragma unroll
      for (int jj = 0; jj < 4; jj++) { bv[jj] = (__bf16)b0[jj]; bv[4 + jj] = (__bf16)b1[jj]; }
      int col = (bc + c * 8) ^ ((br & 7) << 3);
      *(bf16x8*)&Bs[br * 64 + col] = bv;
    }
    __syncthreads();
#pragma unroll
    for (int kk = 0; kk < 2; kk++) {
      bf16x8 afr[2], bfr[4];
#pragma unroll
      for (int mi = 0; mi < 2; mi++) {
        int row = wm + mi * 16 + (lane & 15);
        int col = (kk * 32 + (lane >> 4) * 8) ^ ((row & 7) << 3);
        afr[mi] = *(const bf16x8*)&As[row * 64 + col];
      }
#pragma unroll
      for (int ni = 0; ni < 4; ni++) {
        int row = wn + ni * 16 + (lane & 15);
        int col = (kk * 32 + (lane >> 4) * 8) ^ ((row & 7) << 3);
        bfr[ni] = *(const bf16x8*)&Bs[row * 64 + col];
      }
#pragma unroll
      for (int mi = 0; mi < 2; mi++)
#pragma unroll
        for (int ni = 0; ni < 4; ni++)
          acc[mi][ni] = __builtin_amdgcn_mfma_f32_16x16x32_bf16(afr[mi], bfr[ni], acc[mi][ni], 0, 0, 0);
    }
    __syncthreads();
  }

  // epilogue: RoPE + krot store + V^T via LDS transpose
  float cosv[4], sinv[4];
#pragma unroll
  for (int ni = 0; ni < 4; ni++) {
    int d = wn + ni * 16 + (lane & 15);
    float theta = exp2f((float)(d >> 1) * -0.20762050593046014f); // 10000^(-i/64)
    cosv[ni] = cosf(theta);
    sinv[ni] = sinf(theta);
  }
  __bf16* vl = (__bf16*)psmem; // [64][128]
  const bool evenlane = ((lane & 1) == 0);
#pragma unroll
  for (int mi = 0; mi < 2; mi++) {
#pragma unroll
    for (int r = 0; r < 4; r++) {
      int ml = wm + mi * 16 + (lane >> 4) * 4 + r;
      int mg = m0 + ml;
#pragma unroll
      for (int ni = 0; ni < 4; ni++) {
        float val = acc[mi][ni][r];
        int d = wn + ni * 16 + (lane & 15);
        vl[ml * 128 + d] = (__bf16)val;            // V = pre-RoPE k
        float partner = __shfl_xor(val, 1);
        float e = evenlane ? val : partner;
        float o = evenlane ? partner : val;
        float ev = e * cosv[ni] + o * sinv[ni];
        float od = -ev * sinv[ni] + o * cosv[ni];  // in-place slice semantics
        float kr = evenlane ? ev : od;
        krot[(size_t)mg * 128 + d] = (__bf16)kr;
      }
    }
  }
  __syncthreads();
  {
    int d = tid >> 1;
    int th = tid & 1;
    int b = m0 >> 12;
    int tb = (m0 & 4095) + th * 32;                // 32-aligned
    size_t base = ((size_t)b * 128 + d) * 4096 + tb;
#pragma unroll
    for (int c = 0; c < 4; c++) {
      bf16x8 w;
#pragma unroll
      for (int jj = 0; jj < 8; jj++)
        w[jj] = vl[(th * 32 + vperm(c * 8 + jj)) * 128 + d];
      *(bf16x8*)&vt[base + c * 8] = w;
    }
  }
}

// ---------------- Kernel 2: causal flash attention, swapped 32x32 MFMA ----------------
// block: 256 thr / 4 waves = 2 q-subtiles (32 rows) x 2 kv-splits; q-block 64 rows.
__global__ __launch_bounds__(256, 2) void attn_kernel(
    const __bf16* __restrict__ krot, const __bf16* __restrict__ vt,
    float* __restrict__ out)
{
  __shared__ __align__(16) char smem[65536]; // dbuf: b*32768 + {K p*8192 | 16384 + V p*8192}
  const int tid = threadIdx.x;
  const int wid = tid >> 6;
  const int lane = tid & 63;
  const int lo5 = lane & 31;
  const int hi = lane >> 5;
  const int b = blockIdx.x & 7;                 // batch -> XCD
  const int qb = 63 - (int)(blockIdx.x >> 3);   // 64-row q block, big-first
  const int sub = wid >> 1, split = wid & 1;
  const int q0 = qb * 64 + sub * 32;
  const int jd = qb * 2 + sub;                  // diag kv-tile (32-wide tiles)
  const int njp = qb + 1;                       // super-iterations (pairs of tiles)
  const __bf16* kb = krot + (size_t)b * 4096 * 128;
  const char* vbc = (const char*)(vt + (size_t)b * 128 * 4096);

  // Q fragments (B-operand): q = q0+lo5, k-slice ks: d = ks*16 + hi*8 + j
  bf16x8 qf[8];
  {
    const __bf16* qrow = kb + (size_t)(q0 + lo5) * 128 + hi * 8;
#pragma unroll
    for (int ks = 0; ks < 8; ks++) qf[ks] = *(const bf16x8*)(qrow + ks * 16);
  }

  f32x16 acc[4];
#pragma unroll
  for (int dt = 0; dt < 4; dt++) acc[dt] = (f32x16)0.f;
  float m_r = -1e30f, l_r = 0.f;

#define STAGE(BSEL, JPAIR) do { \
    _Pragma("unroll") \
    for (int p = 0; p < 2; p++) { \
      int kv0_ = ((JPAIR) * 2 + p) * 32; \
      const char* ksrc = (const char*)(kb + (size_t)kv0_ * 128); \
      _Pragma("unroll") \
      for (int h = 0; h < 2; h++) { \
        int Lc = tid + h * 256; \
        int row = Lc >> 4, sp = Lc & 15; \
        gload_lds16(ksrc + row * 256 + (sp ^ (row & 7)) * 16, \
                    smem + (BSEL) * 32768 + p * 8192 + Lc * 16); \
      } \
      _Pragma("unroll") \
      for (int h = 0; h < 2; h++) { \
        int Lc = tid + h * 256; \
        int d_ = Lc >> 2, sp = Lc & 3; \
        gload_lds16(vbc + (size_t)d_ * 8192 + kv0_ * 2 + (sp ^ ((d_ >> 1) & 3)) * 16, \
                    smem + (BSEL) * 32768 + 16384 + p * 8192 + Lc * 16); \
      } \
    } \
  } while (0)

  STAGE(0, 0);
  __syncthreads();

  for (int jp = 0; jp < njp; jp++) {
    STAGE((jp + 1) & 1, (jp + 1 < njp) ? (jp + 1) : 0);   // prefetch (drains at end barrier)
    const int j = jp * 2 + split;
    if (j <= jd) {
      const char* kB = smem + (jp & 1) * 32768 + split * 8192;
      const char* vB = smem + (jp & 1) * 32768 + 16384 + split * 8192;
      const int kv0 = j * 32;
      // QK^T (swapped): S^T[kv][q], col=lo5=q, row=(r&3)+8*(r>>2)+4*hi=kv
      f32x16 S0 = (f32x16)0.f, S1 = (f32x16)0.f;
#pragma unroll
      for (int ks = 0; ks < 4; ks++) {
        bf16x8 kf = *(const bf16x8*)(kB + lo5 * 256 + (((2 * ks + hi) ^ (lo5 & 7)) << 4));
        S0 = __builtin_amdgcn_mfma_f32_32x32x16_bf16(kf, qf[ks], S0, 0, 0, 0);
      }
#pragma unroll
      for (int ks = 4; ks < 8; ks++) {
        bf16x8 kf = *(const bf16x8*)(kB + lo5 * 256 + (((2 * ks + hi) ^ (lo5 & 7)) << 4));
        S1 = __builtin_amdgcn_mfma_f32_32x32x16_bf16(kf, qf[ks], S1, 0, 0, 0);
      }
      f32x16 S = S0 + S1;
      if (j == jd) {
#pragma unroll
        for (int r = 0; r < 16; r++) {
          int kvg = kv0 + (r & 3) + 8 * (r >> 2) + 4 * hi;
          if (kvg > q0 + lo5) S[r] = -1e30f;
        }
      }
      // row max: 16 lane-local + cross-half via shfl_xor(32)
      float pmax = S[0];
#pragma unroll
      for (int r = 1; r < 16; r++) pmax = fmaxf(pmax, S[r]);
      pmax = fmaxf(pmax, __shfl_xor(pmax, 32));
      if (!__all(pmax <= m_r + 24.0f)) {   // defer-max: rescale rarely
        float mnew = fmaxf(m_r, pmax);
        float alpha = exp2f((m_r - mnew) * CEXP);
        m_r = mnew;
        l_r *= alpha;
#pragma unroll
        for (int r = 0; r < 16; r++) {
          int rb = (r & 3) + 8 * (r >> 2);
          float al = readlane_f(alpha, rb), ah = readlane_f(alpha, rb + 4);
          float ar = hi ? ah : al;
#pragma unroll
          for (int dt = 0; dt < 4; dt++) acc[dt][r] *= ar;
        }
      }
      float ps[16];
      float rs = 0.f;
#pragma unroll
      for (int r = 0; r < 16; r++) { ps[r] = exp2f((S[r] - m_r) * CEXP); rs += ps[r]; }
      rs += __shfl_xor(rs, 32);
      l_r += rs;
      // pack P -> A-fragments in NATURAL order (slot j holds kv=(j&3)+8*(j>>2)+4*hi);
      // V's global layout is permuted to the same slot map, so no lane exchange needed.
      union U { __bf16 e[8]; bf16x8 v; };
      U pk0, pk1;
#pragma unroll
      for (int jj = 0; jj < 8; jj++) { pk0.e[jj] = (__bf16)ps[jj]; pk1.e[jj] = (__bf16)ps[8 + jj]; }
      // PV: O[q][d] += P·V ; V frags from permuted V^T LDS tile
#pragma unroll
      for (int dt = 0; dt < 4; dt++) {
        const int d = dt * 32 + lo5;
        const char* vrow = vB + d * 64;
        bf16x8 vf0 = *(const bf16x8*)(vrow + ((hi ^ ((d >> 1) & 3)) << 4));
        bf16x8 vf1 = *(const bf16x8*)(vrow + (((2 + hi) ^ ((d >> 1) & 3)) << 4));
        acc[dt] = __builtin_amdgcn_mfma_f32_32x32x16_bf16(pk0.v, vf0, acc[dt], 0, 0, 0);
        acc[dt] = __builtin_amdgcn_mfma_f32_32x32x16_bf16(pk1.v, vf1, acc[dt], 0, 0, 0);
      }
    }
    __syncthreads();
  }

  // merge kv-splits (pair = sub): split1 -> LDS, split0 merges + stores
  float* mreg = (float*)(smem + sub * 16384);   // [32 q][128 d] f32
  float* mlbuf = (float*)(smem + 32768);        // [2 pairs][2][32]
  if (split == 1) {
#pragma unroll
    for (int r = 0; r < 16; r++) {
      int ql = (r & 3) + 8 * (r >> 2) + 4 * hi;
#pragma unroll
      for (int dt = 0; dt < 4; dt++) mreg[ql * 128 + dt * 32 + lo5] = acc[dt][r];
    }
    if (lane < 32) { mlbuf[sub * 64 + lane] = m_r; mlbuf[sub * 64 + 32 + lane] = l_r; }
  }
  __syncthreads();
  if (split == 0) {
    float mB = mlbuf[sub * 64 + lo5];
    float lB = mlbuf[sub * 64 + 32 + lo5];
    float mstar = fmaxf(m_r, mB);
    float aA = exp2f((m_r - mstar) * CEXP);
    float aB = exp2f((mB - mstar) * CEXP);
    float invl = 1.0f / (l_r * aA + lB * aB);
    float* ob = out + (size_t)b * 4096 * 128;
#pragma unroll
    for (int r = 0; r < 16; r++) {
      const int rb = (r & 3) + 8 * (r >> 2);
      float aAr = hi ? readlane_f(aA, rb + 4) : readlane_f(aA, rb);
      float aBr = hi ? readlane_f(aB, rb + 4) : readlane_f(aB, rb);
      float ivr = hi ? readlane_f(invl, rb + 4) : readlane_f(invl, rb);
      const int ql = rb + 4 * hi;
      const size_t qg = (size_t)(q0 + ql);
#pragma unroll
      for (int dt = 0; dt < 4; dt++) {
        float ov = (acc[dt][r] * aAr + mreg[ql * 128 + dt * 32 + lo5] * aBr) * ivr;
        ob[qg * 128 + dt * 32 + lo5] = ov;
      }
    }
  }
}

extern "C" void kernel_launch(void* const* d_in, const int* in_sizes, int n_in,
                              void* d_out, int out_size, void* d_ws, size_t ws_size,
                              hipStream_t stream) {
  const float* x  = (const float*)d_in[0];
  const float* wk = (const float*)d_in[1];
  __bf16* krot = (__bf16*)d_ws;                       // 8 MB
  __bf16* vt   = krot + (size_t)8 * 4096 * 128;       // 8 MB
  float* out   = (float*)d_out;
  proj_rope_kernel<<<512, 256, 0, stream>>>(x, wk, krot, vt);
  attn_kernel<<<512, 256, 0, stream>>>(krot, vt, out);
}

// Round 5
// 115.152 us; speedup vs baseline: 1.7498x; 1.2271x over previous
//
#include <hip/hip_runtime.h>
#include <hip/hip_bf16.h>
#include <cstdint>

typedef __attribute__((ext_vector_type(8))) __bf16 bf16x8;
typedef __attribute__((ext_vector_type(4))) float f32x4;
typedef __attribute__((ext_vector_type(16))) float f32x16;

typedef const __attribute__((address_space(1))) void* as1cvp;
typedef __attribute__((address_space(3))) void* as3vp;

__device__ __forceinline__ void gload_lds16(const void* g, void* l) {
  __builtin_amdgcn_global_load_lds((as1cvp)g, (as3vp)l, 16, 0, 0);
}
__device__ __forceinline__ float readlane_f(float v, int l) {
  return __uint_as_float((uint32_t)__builtin_amdgcn_readlane((int)__float_as_uint(v), l));
}

// fold sqrt(128^-0.5 * log2e) into krot: S(mfma) = raw * 128^-0.5 * log2e
#define KSCALE 0.3570962f

// V^T t-permutation within each 32-block: new pos p -> old t offset.
__device__ __forceinline__ int vperm(int p) {
  return 16 * (p >> 4) + 4 * ((p >> 3) & 1) + 8 * ((p >> 2) & 1) + (p & 3);
}

// ---------------- Kernel 0: wk f32 -> bf16 (into d_out scratch) ----------------
__global__ __launch_bounds__(256) void wk_convert_kernel(
    const float* __restrict__ wk, __bf16* __restrict__ wkbf) {
  int i = (blockIdx.x * 256 + threadIdx.x) * 4;
  f32x4 v = *(const f32x4*)(wk + i);
  union { __bf16 e[4]; uint64_t u; } p;
#pragma unroll
  for (int j = 0; j < 4; j++) p.e[j] = (__bf16)v[j];
  *(uint64_t*)(wkbf + i) = p.u;
}

// ---------------- Kernel 1: K projection + RoPE + V^T ----------------
// x: [32768][1024] f32 ; wkbf: [128][1024] bf16
// krot: [32768][128] bf16 LINEAR, pre-scaled by KSCALE
// vt:   [8][128][4096] bf16, t permuted within each 32-block by vperm
__global__ __launch_bounds__(256, 4) void proj_rope_kernel(
    const float* __restrict__ x, const __bf16* __restrict__ wkbf,
    __bf16* __restrict__ krot, __bf16* __restrict__ vt)
{
  __shared__ __align__(16) char psmem[40960];
  // As dbuf: [2][32][64] bf16 @0..8192 ; Bs dbuf: [2][128][64] bf16 @8192..40960
  const int tid = threadIdx.x;
  const int wid = tid >> 6;
  const int lane = tid & 63;
  const int m0 = blockIdx.x * 32;
  const int wn = wid * 32;

  f32x4 acc[2][2];
#pragma unroll
  for (int i = 0; i < 2; i++)
#pragma unroll
    for (int j = 0; j < 2; j++) acc[i][j] = (f32x4)0.f;

  const int ar = tid >> 3, ac = (tid & 7) * 8;
  const float* gx0 = x + (size_t)(m0 + ar) * 1024 + ac;

  f32x4 pa0, pa1;
#define LOADA(K0) do { const float* gp = gx0 + (K0); pa0 = *(const f32x4*)gp; pa1 = *(const f32x4*)(gp + 4); } while (0)
#define WRITEA(BUF) do { \
    bf16x8 av; \
    _Pragma("unroll") for (int jj = 0; jj < 4; jj++) { av[jj] = (__bf16)pa0[jj]; av[4 + jj] = (__bf16)pa1[jj]; } \
    *(bf16x8*)((__bf16*)psmem + (BUF) * 2048 + ar * 64 + (ac ^ ((ar & 7) << 3))) = av; \
  } while (0)
#define STAGEB(BUF, K0) do { \
    _Pragma("unroll") for (int h = 0; h < 4; h++) { \
      int Lc = tid + h * 256; int row = Lc >> 3, sp = Lc & 7; \
      gload_lds16((const char*)wkbf + row * 2048 + (K0) * 2 + ((sp ^ (row & 7)) << 4), \
                  psmem + 8192 + (BUF) * 16384 + Lc * 16); \
    } } while (0)

  LOADA(0);
  STAGEB(0, 0);
  WRITEA(0);
  __syncthreads();

  for (int t = 0; t < 16; t++) {
    const int buf = t & 1;
    const bool more = (t + 1 < 16);
    if (more) { LOADA((t + 1) * 64); STAGEB(buf ^ 1, (t + 1) * 64); }
    const __bf16* As = (const __bf16*)psmem + buf * 2048;
    const __bf16* Bs = (const __bf16*)(psmem + 8192 + buf * 16384);
#pragma unroll
    for (int kk = 0; kk < 2; kk++) {
      bf16x8 afr[2], bfr[2];
#pragma unroll
      for (int mi = 0; mi < 2; mi++) {
        int row = mi * 16 + (lane & 15);
        int col = (kk * 32 + (lane >> 4) * 8) ^ ((row & 7) << 3);
        afr[mi] = *(const bf16x8*)&As[row * 64 + col];
      }
#pragma unroll
      for (int ni = 0; ni < 2; ni++) {
        int row = wn + ni * 16 + (lane & 15);
        int col = (kk * 32 + (lane >> 4) * 8) ^ ((row & 7) << 3);
        bfr[ni] = *(const bf16x8*)&Bs[row * 64 + col];
      }
#pragma unroll
      for (int mi = 0; mi < 2; mi++)
#pragma unroll
        for (int ni = 0; ni < 2; ni++)
          acc[mi][ni] = __builtin_amdgcn_mfma_f32_16x16x32_bf16(afr[mi], bfr[ni], acc[mi][ni], 0, 0, 0);
    }
    if (more) WRITEA(buf ^ 1);
    __syncthreads();
  }

  // epilogue: RoPE + scaled krot store + V^T via LDS transpose
  float cosv[2], sinv[2];
#pragma unroll
  for (int ni = 0; ni < 2; ni++) {
    int d = wn + ni * 16 + (lane & 15);
    float theta = exp2f((float)(d >> 1) * -0.20762050593046014f); // 10000^(-i/64)
    cosv[ni] = cosf(theta);
    sinv[ni] = sinf(theta);
  }
  __bf16* vl = (__bf16*)psmem; // [32][128]
  const bool evenlane = ((lane & 1) == 0);
#pragma unroll
  for (int mi = 0; mi < 2; mi++) {
#pragma unroll
    for (int r = 0; r < 4; r++) {
      int ml = mi * 16 + (lane >> 4) * 4 + r;
      int mg = m0 + ml;
#pragma unroll
      for (int ni = 0; ni < 2; ni++) {
        float val = acc[mi][ni][r];
        int d = wn + ni * 16 + (lane & 15);
        vl[ml * 128 + d] = (__bf16)val;            // V = pre-RoPE k, unscaled
        float partner = __shfl_xor(val, 1);
        float e = evenlane ? val : partner;
        float o = evenlane ? partner : val;
        float ev = e * cosv[ni] + o * sinv[ni];
        float od = -ev * sinv[ni] + o * cosv[ni];  // in-place slice semantics
        float kr = evenlane ? ev : od;
        krot[(size_t)mg * 128 + d] = (__bf16)(kr * KSCALE);
      }
    }
  }
  __syncthreads();
  {
    int d = tid >> 1;
    int th = tid & 1;
    int b = m0 >> 12;
    int tb = m0 & 4095;                      // 32-aligned
    size_t base = ((size_t)b * 128 + d) * 4096 + tb;
#pragma unroll
    for (int cc = 0; cc < 2; cc++) {
      int c = th * 2 + cc;
      bf16x8 w;
#pragma unroll
      for (int jj = 0; jj < 8; jj++)
        w[jj] = vl[vperm(c * 8 + jj) * 128 + d];
      *(bf16x8*)&vt[base + c * 8] = w;
    }
  }
}

// ---------------- Kernel 2: causal flash attention, swapped 32x32 MFMA ----------------
__global__ __launch_bounds__(256, 2) void attn_kernel(
    const __bf16* __restrict__ krot, const __bf16* __restrict__ vt,
    float* __restrict__ out)
{
  __shared__ __align__(16) char smem[65536]; // dbuf: b*32768 + {K p*8192 | 16384 + V p*8192}
  const int tid = threadIdx.x;
  const int wid = tid >> 6;
  const int lane = tid & 63;
  const int lo5 = lane & 31;
  const int hi = lane >> 5;
  const int b = blockIdx.x & 7;                 // batch -> XCD
  const int i = (int)(blockIdx.x >> 3);
  const int qb = (i < 32) ? (63 - i) : (i - 32); // balanced pairing: qb(i)+qb(i+32)=63
  const int sub = wid >> 1, split = wid & 1;
  const int q0 = qb * 64 + sub * 32;
  const int jd = qb * 2 + sub;                  // diag kv-tile (32-wide tiles)
  const int njp = qb + 1;                       // super-iterations (pairs of tiles)
  const __bf16* kb = krot + (size_t)b * 4096 * 128;
  const char* vbc = (const char*)(vt + (size_t)b * 128 * 4096);

  // Q fragments (B-operand): q = q0+lo5, k-slice ks: d = ks*16 + hi*8 + j
  bf16x8 qf[8];
  {
    const __bf16* qrow = kb + (size_t)(q0 + lo5) * 128 + hi * 8;
#pragma unroll
    for (int ks = 0; ks < 8; ks++) qf[ks] = *(const bf16x8*)(qrow + ks * 16);
  }

  f32x16 acc[4];
#pragma unroll
  for (int dt = 0; dt < 4; dt++) acc[dt] = (f32x16)0.f;
  float m_r = -1e30f, l_r = 0.f;

#define STAGE(BSEL, JPAIR) do { \
    _Pragma("unroll") \
    for (int p = 0; p < 2; p++) { \
      int kv0_ = ((JPAIR) * 2 + p) * 32; \
      const char* ksrc = (const char*)(kb + (size_t)kv0_ * 128); \
      _Pragma("unroll") \
      for (int h = 0; h < 2; h++) { \
        int Lc = tid + h * 256; \
        int row = Lc >> 4, sp = Lc & 15; \
        gload_lds16(ksrc + row * 256 + (sp ^ (row & 15)) * 16, \
                    smem + (BSEL) * 32768 + p * 8192 + Lc * 16); \
      } \
      _Pragma("unroll") \
      for (int h = 0; h < 2; h++) { \
        int Lc = tid + h * 256; \
        int d_ = Lc >> 2, sp = Lc & 3; \
        gload_lds16(vbc + (size_t)d_ * 8192 + kv0_ * 2 + (sp ^ ((d_ >> 1) & 3)) * 16, \
                    smem + (BSEL) * 32768 + 16384 + p * 8192 + Lc * 16); \
      } \
    } \
  } while (0)

  STAGE(0, 0);
  __syncthreads();

  for (int jp = 0; jp < njp; jp++) {
    STAGE((jp + 1) & 1, (jp + 1 < njp) ? (jp + 1) : 0);   // prefetch (drains at end barrier)
    const int j = jp * 2 + split;
    if (j <= jd) {
      const char* kB = smem + (jp & 1) * 32768 + split * 8192;
      const char* vB = smem + (jp & 1) * 32768 + 16384 + split * 8192;
      const int kv0 = j * 32;
      // QK^T (swapped): S^T[kv][q], col=lo5=q, row=(r&3)+8*(r>>2)+4*hi=kv
      f32x16 S0 = (f32x16)0.f, S1 = (f32x16)0.f;
      __builtin_amdgcn_s_setprio(1);
#pragma unroll
      for (int ks = 0; ks < 4; ks++) {
        bf16x8 kf = *(const bf16x8*)(kB + lo5 * 256 + (((2 * ks + hi) ^ (lo5 & 15)) << 4));
        S0 = __builtin_amdgcn_mfma_f32_32x32x16_bf16(kf, qf[ks], S0, 0, 0, 0);
      }
#pragma unroll
      for (int ks = 4; ks < 8; ks++) {
        bf16x8 kf = *(const bf16x8*)(kB + lo5 * 256 + (((2 * ks + hi) ^ (lo5 & 15)) << 4));
        S1 = __builtin_amdgcn_mfma_f32_32x32x16_bf16(kf, qf[ks], S1, 0, 0, 0);
      }
      __builtin_amdgcn_s_setprio(0);
      f32x16 S = S0 + S1;
      if (j == jd) {
#pragma unroll
        for (int r = 0; r < 16; r++) {
          int kvg = kv0 + (r & 3) + 8 * (r >> 2) + 4 * hi;
          if (kvg > q0 + lo5) S[r] = -1e30f;
        }
      }
      // row max: 16 lane-local + cross-half via shfl_xor(32)
      float pmax = S[0];
#pragma unroll
      for (int r = 1; r < 16; r++) pmax = fmaxf(pmax, S[r]);
      pmax = fmaxf(pmax, __shfl_xor(pmax, 32));
      if (!__all(pmax <= m_r + 12.0f)) {   // defer-max: rescale rarely
        float mnew = fmaxf(m_r, pmax);
        float alpha = exp2f(m_r - mnew);
        m_r = mnew;
        l_r *= alpha;
#pragma unroll
        for (int r = 0; r < 16; r++) {
          int rb = (r & 3) + 8 * (r >> 2);
          float al = readlane_f(alpha, rb), ah = readlane_f(alpha, rb + 4);
          float ar = hi ? ah : al;
#pragma unroll
          for (int dt = 0; dt < 4; dt++) acc[dt][r] *= ar;
        }
      }
      float ps[16];
      float rs = 0.f;
#pragma unroll
      for (int r = 0; r < 16; r++) { ps[r] = exp2f(S[r] - m_r); rs += ps[r]; }
      rs += __shfl_xor(rs, 32);
      l_r += rs;
      // pack P -> A-fragments in NATURAL order (slot j holds kv=(j&3)+8*(j>>2)+4*hi);
      // V's global layout is permuted to the same slot map (vperm).
      union U { __bf16 e[8]; bf16x8 v; };
      U pk0, pk1;
#pragma unroll
      for (int jj = 0; jj < 8; jj++) { pk0.e[jj] = (__bf16)ps[jj]; pk1.e[jj] = (__bf16)ps[8 + jj]; }
      __builtin_amdgcn_s_setprio(1);
#pragma unroll
      for (int dt = 0; dt < 4; dt++) {
        const int d = dt * 32 + lo5;
        const char* vrow = vB + d * 64;
        bf16x8 vf0 = *(const bf16x8*)(vrow + ((hi ^ ((d >> 1) & 3)) << 4));
        bf16x8 vf1 = *(const bf16x8*)(vrow + (((2 + hi) ^ ((d >> 1) & 3)) << 4));
        acc[dt] = __builtin_amdgcn_mfma_f32_32x32x16_bf16(pk0.v, vf0, acc[dt], 0, 0, 0);
        acc[dt] = __builtin_amdgcn_mfma_f32_32x32x16_bf16(pk1.v, vf1, acc[dt], 0, 0, 0);
      }
      __builtin_amdgcn_s_setprio(0);
    }
    __syncthreads();
  }

  // merge kv-splits (pair = sub): split1 -> LDS, split0 merges + stores
  float* mreg = (float*)(smem + sub * 16384);   // [32 q][128 d] f32
  float* mlbuf = (float*)(smem + 32768);        // [2 pairs][2][32]
  if (split == 1) {
#pragma unroll
    for (int r = 0; r < 16; r++) {
      int ql = (r & 3) + 8 * (r >> 2) + 4 * hi;
#pragma unroll
      for (int dt = 0; dt < 4; dt++) mreg[ql * 128 + dt * 32 + lo5] = acc[dt][r];
    }
    if (lane < 32) { mlbuf[sub * 64 + lane] = m_r; mlbuf[sub * 64 + 32 + lane] = l_r; }
  }
  __syncthreads();
  if (split == 0) {
    float mB = mlbuf[sub * 64 + lo5];
    float lB = mlbuf[sub * 64 + 32 + lo5];
    float mstar = fmaxf(m_r, mB);
    float aA = exp2f(m_r - mstar);
    float aB = exp2f(mB - mstar);
    float invl = 1.0f / (l_r * aA + lB * aB);
    float* ob = out + (size_t)b * 4096 * 128;
#pragma unroll
    for (int r = 0; r < 16; r++) {
      const int rb = (r & 3) + 8 * (r >> 2);
      float aAr = hi ? readlane_f(aA, rb + 4) : readlane_f(aA, rb);
      float aBr = hi ? readlane_f(aB, rb + 4) : readlane_f(aB, rb);
      float ivr = hi ? readlane_f(invl, rb + 4) : readlane_f(invl, rb);
      const int ql = rb + 4 * hi;
      const size_t qg = (size_t)(q0 + ql);
#pragma unroll
      for (int dt = 0; dt < 4; dt++) {
        float ov = (acc[dt][r] * aAr + mreg[ql * 128 + dt * 32 + lo5] * aBr) * ivr;
        ob[qg * 128 + dt * 32 + lo5] = ov;
      }
    }
  }
}

extern "C" void kernel_launch(void* const* d_in, const int* in_sizes, int n_in,
                              void* d_out, int out_size, void* d_ws, size_t ws_size,
                              hipStream_t stream) {
  const float* x  = (const float*)d_in[0];
  const float* wk = (const float*)d_in[1];
  __bf16* krot = (__bf16*)d_ws;                       // 8 MB
  __bf16* vt   = krot + (size_t)8 * 4096 * 128;       // 8 MB
  float* out   = (float*)d_out;
  __bf16* wkbf = (__bf16*)d_out;                      // 256 KB scratch in d_out; attn overwrites
  wk_convert_kernel<<<128, 256, 0, stream>>>(wk, wkbf);
  proj_rope_kernel<<<1024, 256, 0, stream>>>(x, wkbf, krot, vt);
  attn_kernel<<<512, 256, 0, stream>>>(krot, vt, out);
}

// Round 6
// 93.470 us; speedup vs baseline: 2.1556x; 1.2320x over previous
//
#include <hip/hip_runtime.h>
#include <hip/hip_bf16.h>
#include <cstdint>

typedef __attribute__((ext_vector_type(8))) __bf16 bf16x8;
typedef __attribute__((ext_vector_type(4))) float f32x4;
typedef __attribute__((ext_vector_type(16))) float f32x16;

typedef const __attribute__((address_space(1))) void* as1cvp;
typedef __attribute__((address_space(3))) void* as3vp;

__device__ __forceinline__ void gload_lds16(const void* g, void* l) {
  __builtin_amdgcn_global_load_lds((as1cvp)g, (as3vp)l, 16, 0, 0);
}
__device__ __forceinline__ float readlane_f(float v, int l) {
  return __uint_as_float((uint32_t)__builtin_amdgcn_readlane((int)__float_as_uint(v), l));
}

// fold sqrt(128^-0.5 * log2e) into k2: S(mfma) = raw * 128^-0.5 * log2e
#define KSCALE 0.3570962f

// V^T t-permutation within each 32-block: new pos p -> old t offset.
__device__ __forceinline__ int vperm(int p) {
  return 16 * (p >> 4) + 4 * ((p >> 3) & 1) + 8 * ((p >> 2) & 1) + (p & 3);
}

// ---------------- Kernel 0: wk f32 -> bf16 (into d_out scratch) ----------------
__global__ __launch_bounds__(256) void wk_convert_kernel(
    const float* __restrict__ wk, __bf16* __restrict__ wkbf) {
  int i = (blockIdx.x * 256 + threadIdx.x) * 4;
  f32x4 v = *(const f32x4*)(wk + i);
  union { __bf16 e[4]; uint64_t u; } p;
#pragma unroll
  for (int j = 0; j < 4; j++) p.e[j] = (__bf16)v[j];
  *(uint64_t*)(wkbf + i) = p.u;
}

// ---------------- Kernel 1: K projection + RoPE, fragment-tiled outputs ----------------
// x: [32768][1024] f32 ; wkbf: [128][1024] bf16
// k2:  [1024 tiles][16 slot][32 kv][8] bf16  (tile = global t/32; KSCALE-scaled rotated K)
//      element = krot[t=T*32+kv][d=s*8+j]
// vt3: [1024 tiles][4 chunk][128 d][8] bf16  (pre-RoPE V, t-permuted: t = T*32 + vperm(c*8+j))
__global__ __launch_bounds__(256, 4) void proj_rope_kernel(
    const float* __restrict__ x, const __bf16* __restrict__ wkbf,
    __bf16* __restrict__ k2, __bf16* __restrict__ vt3)
{
  __shared__ __align__(16) char psmem[40960];
  // As dbuf: [2][32][64] bf16 @0..8192 ; Bs dbuf: [2][128][64] bf16 @8192..40960
  const int tid = threadIdx.x;
  const int wid = tid >> 6;
  const int lane = tid & 63;
  const int m0 = blockIdx.x * 32;
  const int wn = wid * 32;

  f32x4 acc[2][2];
#pragma unroll
  for (int i = 0; i < 2; i++)
#pragma unroll
    for (int j = 0; j < 2; j++) acc[i][j] = (f32x4)0.f;

  const int ar = tid >> 3, ac = (tid & 7) * 8;
  const float* gx0 = x + (size_t)(m0 + ar) * 1024 + ac;

  f32x4 pa0, pa1;
#define LOADA(K0) do { const float* gp = gx0 + (K0); pa0 = *(const f32x4*)gp; pa1 = *(const f32x4*)(gp + 4); } while (0)
#define WRITEA(BUF) do { \
    bf16x8 av; \
    _Pragma("unroll") for (int jj = 0; jj < 4; jj++) { av[jj] = (__bf16)pa0[jj]; av[4 + jj] = (__bf16)pa1[jj]; } \
    *(bf16x8*)((__bf16*)psmem + (BUF) * 2048 + ar * 64 + (ac ^ ((ar & 7) << 3))) = av; \
  } while (0)
#define STAGEB(BUF, K0) do { \
    _Pragma("unroll") for (int h = 0; h < 4; h++) { \
      int Lc = tid + h * 256; int row = Lc >> 3, sp = Lc & 7; \
      gload_lds16((const char*)wkbf + row * 2048 + (K0) * 2 + ((sp ^ (row & 7)) << 4), \
                  psmem + 8192 + (BUF) * 16384 + Lc * 16); \
    } } while (0)

  LOADA(0);
  STAGEB(0, 0);
  WRITEA(0);
  __syncthreads();

  for (int t = 0; t < 16; t++) {
    const int buf = t & 1;
    const bool more = (t + 1 < 16);
    if (more) { LOADA((t + 1) * 64); STAGEB(buf ^ 1, (t + 1) * 64); }
    const __bf16* As = (const __bf16*)psmem + buf * 2048;
    const __bf16* Bs = (const __bf16*)(psmem + 8192 + buf * 16384);
#pragma unroll
    for (int kk = 0; kk < 2; kk++) {
      bf16x8 afr[2], bfr[2];
#pragma unroll
      for (int mi = 0; mi < 2; mi++) {
        int row = mi * 16 + (lane & 15);
        int col = (kk * 32 + (lane >> 4) * 8) ^ ((row & 7) << 3);
        afr[mi] = *(const bf16x8*)&As[row * 64 + col];
      }
#pragma unroll
      for (int ni = 0; ni < 2; ni++) {
        int row = wn + ni * 16 + (lane & 15);
        int col = (kk * 32 + (lane >> 4) * 8) ^ ((row & 7) << 3);
        bfr[ni] = *(const bf16x8*)&Bs[row * 64 + col];
      }
#pragma unroll
      for (int mi = 0; mi < 2; mi++)
#pragma unroll
        for (int ni = 0; ni < 2; ni++)
          acc[mi][ni] = __builtin_amdgcn_mfma_f32_16x16x32_bf16(afr[mi], bfr[ni], acc[mi][ni], 0, 0, 0);
    }
    if (more) WRITEA(buf ^ 1);
    __syncthreads();
  }

  // epilogue: RoPE; stage V (vl) and scaled K (kl_e, col-swizzled) in LDS
  float cosv[2], sinv[2];
#pragma unroll
  for (int ni = 0; ni < 2; ni++) {
    int d = wn + ni * 16 + (lane & 15);
    float theta = exp2f((float)(d >> 1) * -0.20762050593046014f); // 10000^(-i/64)
    cosv[ni] = cosf(theta);
    sinv[ni] = sinf(theta);
  }
  __bf16* vl = (__bf16*)psmem;             // [32][128]
  __bf16* kl_e = (__bf16*)(psmem + 8192);  // [32][128], col ^ ((row&15)<<3)
  const bool evenlane = ((lane & 1) == 0);
#pragma unroll
  for (int mi = 0; mi < 2; mi++) {
#pragma unroll
    for (int r = 0; r < 4; r++) {
      int ml = mi * 16 + (lane >> 4) * 4 + r;
#pragma unroll
      for (int ni = 0; ni < 2; ni++) {
        float val = acc[mi][ni][r];
        int d = wn + ni * 16 + (lane & 15);
        vl[ml * 128 + d] = (__bf16)val;            // V = pre-RoPE k, unscaled
        float partner = __shfl_xor(val, 1);
        float e = evenlane ? val : partner;
        float o = evenlane ? partner : val;
        float ev = e * cosv[ni] + o * sinv[ni];
        float od = -ev * sinv[ni] + o * cosv[ni];  // in-place slice semantics
        float kr = evenlane ? ev : od;
        kl_e[ml * 128 + (d ^ ((ml & 15) << 3))] = (__bf16)(kr * KSCALE);
      }
    }
  }
  __syncthreads();
  const size_t T = blockIdx.x;
  {
    // K out: k2[T][s][kv][8]
    int s = tid >> 4, kvb = tid & 15;
    __bf16* kg = k2 + T * 4096 + s * 256;
#pragma unroll
    for (int h = 0; h < 2; h++) {
      int kv = kvb + h * 16;
      bf16x8 w = *(const bf16x8*)&kl_e[kv * 128 + ((s * 8) ^ ((kv & 15) << 3))];
      *(bf16x8*)(kg + kv * 8) = w;
    }
  }
  {
    // V out: vt3[T][c][d][8], t-permuted
    int d = tid >> 1, th = tid & 1;
    __bf16* vg = vt3 + T * 4096 + d * 8;
#pragma unroll
    for (int cc = 0; cc < 2; cc++) {
      int c = 2 * th + cc;
      bf16x8 w;
#pragma unroll
      for (int jj = 0; jj < 8; jj++)
        w[jj] = vl[vperm(c * 8 + jj) * 128 + d];
      *(bf16x8*)(vg + c * 1024) = w;
    }
  }
}

// ---------------- Kernel 2: causal flash attention, direct-from-L2, no loop barriers ----------------
__global__ __launch_bounds__(256, 2) void attn_kernel(
    const __bf16* __restrict__ k2, const __bf16* __restrict__ vt3,
    float* __restrict__ out)
{
  __shared__ __align__(16) char smem[33280]; // merge: [2][32][128] f32 + mlbuf
  const int tid = threadIdx.x;
  const int wid = tid >> 6;
  const int lane = tid & 63;
  const int lo5 = lane & 31;
  const int hi = lane >> 5;
  const int b = blockIdx.x & 7;                 // batch -> XCD (K/V L2-resident)
  const int i = (int)(blockIdx.x >> 3);
  const int qb = (i < 32) ? (63 - i) : (i - 32); // balanced pairing: co-resident pairs sum const
  const int sub = wid >> 1, split = wid & 1;
  const int q0 = qb * 64 + sub * 32;
  const int jd = qb * 2 + sub;                  // diag 32-kv tile
  const __bf16* kt = k2 + (size_t)b * 524288;
  const __bf16* vb = vt3 + (size_t)b * 524288;

  // Q fragments: q row = lo5 within tile (2qb+sub); slot s=2ks+hi
  bf16x8 qf[8];
  {
    const __bf16* qp = kt + (size_t)(2 * qb + sub) * 4096 + lo5 * 8;
#pragma unroll
    for (int ks = 0; ks < 8; ks++) qf[ks] = *(const bf16x8*)(qp + (2 * ks + hi) * 256);
  }

  f32x16 acc[4];
#pragma unroll
  for (int dt = 0; dt < 4; dt++) acc[dt] = (f32x16)0.f;
  float m_r = -1e30f, l_r = 0.f;

  for (int j = split; j <= jd; j += 2) {
    const __bf16* kp = kt + (size_t)j * 4096 + lo5 * 8;
    const __bf16* vp = vb + (size_t)j * 4096 + lo5 * 8;
    bf16x8 kf[8];
#pragma unroll
    for (int ks = 0; ks < 8; ks++) kf[ks] = *(const bf16x8*)(kp + (2 * ks + hi) * 256);
    bf16x8 vf0[4], vf1[4];
#pragma unroll
    for (int dt = 0; dt < 4; dt++) {
      vf0[dt] = *(const bf16x8*)(vp + hi * 1024 + dt * 256);
      vf1[dt] = *(const bf16x8*)(vp + (2 + hi) * 1024 + dt * 256);
    }
    // QK^T (swapped): S^T[kv][q], col=lo5=q, kv=(r&3)+8*(r>>2)+4*hi
    f32x16 S = (f32x16)0.f;
    __builtin_amdgcn_s_setprio(1);
#pragma unroll
    for (int ks = 0; ks < 8; ks++)
      S = __builtin_amdgcn_mfma_f32_32x32x16_bf16(kf[ks], qf[ks], S, 0, 0, 0);
    __builtin_amdgcn_s_setprio(0);
    if (j == jd) {
      const int kv0 = j * 32;
#pragma unroll
      for (int r = 0; r < 16; r++) {
        int kvg = kv0 + (r & 3) + 8 * (r >> 2) + 4 * hi;
        if (kvg > q0 + lo5) S[r] = -1e30f;
      }
    }
    // row max: pairwise tree (fmax fuses to max3) + cross-half
    float t8[8];
#pragma unroll
    for (int r = 0; r < 8; r++) t8[r] = fmaxf(S[2 * r], S[2 * r + 1]);
#pragma unroll
    for (int r = 0; r < 4; r++) t8[r] = fmaxf(t8[r], t8[r + 4]);
    t8[0] = fmaxf(fmaxf(t8[0], t8[1]), fmaxf(t8[2], t8[3]));
    float pmax = fmaxf(t8[0], __shfl_xor(t8[0], 32));
    if (!__all(pmax <= m_r + 12.0f)) {   // defer-max: rescale rarely
      float mnew = fmaxf(m_r, pmax);
      float alpha = exp2f(m_r - mnew);
      m_r = mnew;
      l_r *= alpha;
#pragma unroll
      for (int r = 0; r < 16; r++) {
        int rb = (r & 3) + 8 * (r >> 2);
        float al = readlane_f(alpha, rb), ah = readlane_f(alpha, rb + 4);
        float ar = hi ? ah : al;
#pragma unroll
        for (int dt = 0; dt < 4; dt++) acc[dt][r] *= ar;
      }
    }
    float ps[16];
    float rs = 0.f;
#pragma unroll
    for (int r = 0; r < 16; r++) { ps[r] = exp2f(S[r] - m_r); rs += ps[r]; }
    rs += __shfl_xor(rs, 32);
    l_r += rs;
    // P -> A-frags in natural order (slot j: kv=(j&3)+8*(j>>2)+4*hi); vt3 is permuted to match
    union U { __bf16 e[8]; bf16x8 v; };
    U pk0, pk1;
#pragma unroll
    for (int jj = 0; jj < 8; jj++) { pk0.e[jj] = (__bf16)ps[jj]; pk1.e[jj] = (__bf16)ps[8 + jj]; }
    __builtin_amdgcn_s_setprio(1);
#pragma unroll
    for (int dt = 0; dt < 4; dt++)
      acc[dt] = __builtin_amdgcn_mfma_f32_32x32x16_bf16(pk0.v, vf0[dt], acc[dt], 0, 0, 0);
#pragma unroll
    for (int dt = 0; dt < 4; dt++)
      acc[dt] = __builtin_amdgcn_mfma_f32_32x32x16_bf16(pk1.v, vf1[dt], acc[dt], 0, 0, 0);
    __builtin_amdgcn_s_setprio(0);
  }

  // merge kv-splits: split1 -> LDS, split0 merges + stores
  float* mreg = (float*)smem + sub * 4096;      // [32 q][128 d]
  float* mlbuf = (float*)(smem + 32768);        // [2 subs][2][32]
  if (split == 1) {
#pragma unroll
    for (int r = 0; r < 16; r++) {
      int ql = (r & 3) + 8 * (r >> 2) + 4 * hi;
#pragma unroll
      for (int dt = 0; dt < 4; dt++) mreg[ql * 128 + dt * 32 + lo5] = acc[dt][r];
    }
    if (lane < 32) { mlbuf[sub * 64 + lane] = m_r; mlbuf[sub * 64 + 32 + lane] = l_r; }
  }
  __syncthreads();
  if (split == 0) {
    float mB = mlbuf[sub * 64 + lo5];
    float lB = mlbuf[sub * 64 + 32 + lo5];
    float mstar = fmaxf(m_r, mB);
    float aA = exp2f(m_r - mstar);
    float aB = exp2f(mB - mstar);
    float invl = 1.0f / (l_r * aA + lB * aB);
    float* ob = out + (size_t)b * 4096 * 128;
#pragma unroll
    for (int r = 0; r < 16; r++) {
      const int rb = (r & 3) + 8 * (r >> 2);
      float aAr = hi ? readlane_f(aA, rb + 4) : readlane_f(aA, rb);
      float aBr = hi ? readlane_f(aB, rb + 4) : readlane_f(aB, rb);
      float ivr = hi ? readlane_f(invl, rb + 4) : readlane_f(invl, rb);
      const int ql = rb + 4 * hi;
      const size_t qg = (size_t)(q0 + ql);
#pragma unroll
      for (int dt = 0; dt < 4; dt++) {
        float ov = (acc[dt][r] * aAr + mreg[ql * 128 + dt * 32 + lo5] * aBr) * ivr;
        ob[qg * 128 + dt * 32 + lo5] = ov;
      }
    }
  }
}

extern "C" void kernel_launch(void* const* d_in, const int* in_sizes, int n_in,
                              void* d_out, int out_size, void* d_ws, size_t ws_size,
                              hipStream_t stream) {
  const float* x  = (const float*)d_in[0];
  const float* wk = (const float*)d_in[1];
  __bf16* k2  = (__bf16*)d_ws;                        // 8 MB, fragment-tiled K
  __bf16* vt3 = k2 + (size_t)8 * 4096 * 128;          // 8 MB, fragment-tiled V
  float* out  = (float*)d_out;
  __bf16* wkbf = (__bf16*)d_out;                      // 256 KB scratch in d_out; attn overwrites
  wk_convert_kernel<<<128, 256, 0, stream>>>(wk, wkbf);
  proj_rope_kernel<<<1024, 256, 0, stream>>>(x, wkbf, k2, vt3);
  attn_kernel<<<512, 256, 0, stream>>>(k2, vt3, out);
}